// Round 4
// baseline (363.733 us; speedup 1.0000x reference)
//
#include <hip/hip_runtime.h>
#include <cstdint>

#define B_SZ 8192
#define IN_SZ 1024
#define H_SZ 1024

typedef unsigned short u16;
typedef __bf16 bf16_t;
typedef bf16_t bf16x8 __attribute__((ext_vector_type(8)));
typedef float floatx4 __attribute__((ext_vector_type(4)));

// s_waitcnt immediates: [3:0]=vmcnt low, [6:4]=expcnt(7=nowait), [11:8]=lgkmcnt(15=nowait)
#define WAITCNT_VM4 0xF74
#define WAITCNT_VM3 0xF73
#define WAITCNT_VM0 0xF70

__device__ __forceinline__ u16 f2bf(float f) {
    unsigned int u = __float_as_uint(f);
    u += 0x7fffu + ((u >> 16) & 1u);   // RNE
    return (u16)(u >> 16);
}
__device__ __forceinline__ float bf2f(u16 b) {
    return __uint_as_float(((unsigned int)b) << 16);
}

// async global->LDS, 16B per lane; LDS dest = wave-uniform base + lane*16
__device__ __forceinline__ void g2l16(const u16* g, u16* l) {
    __builtin_amdgcn_global_load_lds(
        (__attribute__((address_space(1))) void*)(uintptr_t)g,
        (__attribute__((address_space(3))) void*)(uint32_t)(uintptr_t)l,
        16, 0, 0);
}

// ---------------- single fp32 -> bf16 conversion dispatch ----------------
__global__ __launch_bounds__(256) void cvt_all(
    const float* __restrict__ X, const float* __restrict__ Hd,
    const float* __restrict__ w0, const float* __restrict__ w1,
    const float* __restrict__ w2, const float* __restrict__ w3,
    const float* __restrict__ w4, const float* __restrict__ w5,
    u16* __restrict__ Xb, u16* __restrict__ Hb,
    u16* __restrict__ d0, u16* __restrict__ d1, u16* __restrict__ d2,
    u16* __restrict__ d3, u16* __restrict__ d4, u16* __restrict__ d5) {
    const int b = blockIdx.x;
    const int tid = threadIdx.x;
    const float* s; u16* d; int off;
    if (b < 8192) {
        s = X; d = Xb; off = b * 256 + tid;
    } else if (b < 16384) {
        s = Hd; d = Hb; off = (b - 8192) * 256 + tid;
    } else {
        const int wb = b - 16384;
        const int w = wb >> 10;
        off = ((wb & 1023) << 8) + tid;
        switch (w) {
            case 0: s = w0; d = d0; break;
            case 1: s = w1; d = d1; break;
            case 2: s = w2; d = d2; break;
            case 3: s = w3; d = d3; break;
            case 4: s = w4; d = d4; break;
            default: s = w5; d = d5; break;
        }
    }
    float4 v = ((const float4*)s)[off];
    ushort4 o;
    o.x = f2bf(v.x); o.y = f2bf(v.y); o.z = f2bf(v.z); o.w = f2bf(v.w);
    ((ushort4*)d)[off] = o;
}

// ---------------- dispatch B: r, z, P; 1D grid 1536 ----------------
// 3-deep LDS rotation, manual vmcnt + raw s_barrier: loads for iter k+2 are
// issued at iter k -> 2 wall-iterations of in-flight time (covers HBM miss).
// Per wave: 4 g2l16 per stage. At iter top: wait vmcnt(4) => this iter's 4
// loads done (next iter's 4 still in flight); barrier => ALL waves' tiles in.
__global__ __launch_bounds__(256) void gemm_rzp(
    const u16* __restrict__ Xb, const u16* __restrict__ Hb,
    const u16* __restrict__ Wr0, const u16* __restrict__ Wr1,
    const u16* __restrict__ Wz0, const u16* __restrict__ Wz1,
    const u16* __restrict__ Wh0,
    const float* __restrict__ bir, const float* __restrict__ bhr,
    const float* __restrict__ biz, const float* __restrict__ bhz,
    const float* __restrict__ bih,
    const float* __restrict__ hidden,
    u16* __restrict__ RHb, u16* __restrict__ Zb, u16* __restrict__ Pb) {
    constexpr int BM = 128, BN = 128, BK = 32, K = 1024;
    constexpr int TSZ = BM * BK;           // 4096 u16 = 8KB per buffer
    __shared__ u16 As[3 * TSZ];            // 24KB
    __shared__ u16 Bs[3 * TSZ];            // 24KB
    const int tid = threadIdx.x;
    const int wave = tid >> 6;
    const int lane = tid & 63;
    const int idx = blockIdx.x;
    const int bn = idx & 7;                // XCD-local weight column
    const int gate = (idx >> 3) % 3;
    const int bm = idx / 24;
    const int wr = wave >> 1, wc = wave & 1;   // 2x2 waves, 64x64 each

    const u16* Bg0 = (gate == 0) ? Wr0 : (gate == 1) ? Wz0 : Wh0;
    const u16* Bg1 = (gate == 0) ? Wr1 : Wz1;   // unused when gate==2
    const int NT = (gate == 2) ? 32 : 64;

    const floatx4 z4 = {0.f, 0.f, 0.f, 0.f};
    floatx4 acc[4][4];
#pragma unroll
    for (int i = 0; i < 4; ++i)
#pragma unroll
        for (int j = 0; j < 4; ++j) acc[i][j] = z4;

    auto stage = [&](int pb, int kt) {
        const int seg = kt >> 5;
        const int k0 = (kt & 31) * BK;
        const u16* __restrict__ Ag = seg ? Hb : Xb;
        const u16* __restrict__ Bg = seg ? Bg1 : Bg0;
        const int base = pb * TSZ;
#pragma unroll
        for (int j = 0; j < 2; ++j) {
            const int c = j * 256 + wave * 64 + lane;   // 16B chunk 0..511
            const int row = c >> 2;
            const int s16 = c & 3;
            const int ldsc = base + (j * 256 + wave * 64) * 8;  // wave-uniform
            g2l16(Ag + (size_t)(bm * BM + row) * K + k0 + s16 * 8, &As[ldsc]);
            g2l16(Bg + (size_t)(bn * BN + row) * K + k0 + s16 * 8, &Bs[ldsc]);
        }
    };

    stage(0, 0);
    stage(1, 1);
    const int mr = lane & 15;
    const int q8 = (lane >> 4) * 8;
    for (int kt = 0; kt < NT; ++kt) {
        if (kt < NT - 1) __builtin_amdgcn_s_waitcnt(WAITCNT_VM4);
        else             __builtin_amdgcn_s_waitcnt(WAITCNT_VM0);
        __builtin_amdgcn_s_barrier();
        if (kt + 2 < NT) stage((kt + 2) % 3, kt + 2);
        const int cb = (kt % 3) * TSZ;
        bf16x8 af[4], bfv[4];
#pragma unroll
        for (int i = 0; i < 4; ++i)
            af[i] = *(const bf16x8*)&As[cb + (wr * 64 + i * 16 + mr) * BK + q8];
#pragma unroll
        for (int j = 0; j < 4; ++j)
            bfv[j] = *(const bf16x8*)&Bs[cb + (wc * 64 + j * 16 + mr) * BK + q8];
#pragma unroll
        for (int i = 0; i < 4; ++i)
#pragma unroll
            for (int j = 0; j < 4; ++j)
                acc[i][j] = __builtin_amdgcn_mfma_f32_16x16x32_bf16(
                    af[i], bfv[j], acc[i][j], 0, 0, 0);
    }

    // C/D layout: col=lane&15, row=(lane>>4)*4+reg (m89/m91 verified)
    const int colBase = bn * BN + wc * 64 + (lane & 15);
    const int rowBase = bm * BM + wr * 64 + (lane >> 4) * 4;
#pragma unroll
    for (int j = 0; j < 4; ++j) {
        const int coln = colBase + j * 16;
        float bias;
        if (gate == 0) bias = bir[coln] + bhr[coln];
        else if (gate == 1) bias = biz[coln] + bhz[coln];
        else bias = bih[coln];
#pragma unroll
        for (int i = 0; i < 4; ++i) {
#pragma unroll
            for (int r = 0; r < 4; ++r) {
                const int rown = rowBase + i * 16 + r;
                const size_t oidx = (size_t)rown * H_SZ + coln;
                const float v = acc[i][j][r] + bias;
                if (gate == 0) {
                    const float rv = 1.0f / (1.0f + __expf(-v));
                    RHb[oidx] = f2bf(rv * hidden[oidx]);
                } else if (gate == 1) {
                    Zb[oidx] = f2bf(1.0f / (1.0f + __expf(-v)));
                } else {
                    Pb[oidx] = f2bf(v);
                }
            }
        }
    }
}

// ---------------- dispatch C: new_hidden; 1D grid 1024 ----------------
// BM=128 BN=64; 3-deep rotation (36KB LDS -> 4 blocks/CU); 3 g2l16/stage/wave
__global__ __launch_bounds__(256) void gemm_nh(
    const u16* __restrict__ RHb, const u16* __restrict__ Whh,
    const float* __restrict__ bhh,
    const u16* __restrict__ Pb, const u16* __restrict__ Zb,
    const float* __restrict__ hidden, float* __restrict__ out_nh) {
    constexpr int BM = 128, BN = 64, BK = 32, K = 1024, NT = K / BK;
    constexpr int ASZ = BM * BK;   // 4096 u16
    constexpr int BSZ = BN * BK;   // 2048 u16
    __shared__ u16 As[3 * ASZ];    // 24KB
    __shared__ u16 Bs[3 * BSZ];    // 12KB
    const int tid = threadIdx.x;
    const int wave = tid >> 6;
    const int lane = tid & 63;
    const int bn = blockIdx.x & 15;
    const int bm = blockIdx.x >> 4;
    const int wr = wave >> 1, wc = wave & 1;   // 64 rows x 32 cols per wave

    const floatx4 z4 = {0.f, 0.f, 0.f, 0.f};
    floatx4 acc[4][2];
#pragma unroll
    for (int i = 0; i < 4; ++i)
#pragma unroll
        for (int j = 0; j < 2; ++j) acc[i][j] = z4;

    auto stage = [&](int pb, int kt) {
        const int k0 = kt * BK;
#pragma unroll
        for (int j = 0; j < 2; ++j) {
            const int c = j * 256 + wave * 64 + lane;
            const int row = c >> 2;
            const int s16 = c & 3;
            const int ldsc = pb * ASZ + (j * 256 + wave * 64) * 8;
            g2l16(RHb + (size_t)(bm * BM + row) * K + k0 + s16 * 8, &As[ldsc]);
        }
        {
            const int c = wave * 64 + lane;
            const int row = c >> 2;
            const int s16 = c & 3;
            const int ldsc = pb * BSZ + (wave * 64) * 8;
            g2l16(Whh + (size_t)(bn * BN + row) * K + k0 + s16 * 8, &Bs[ldsc]);
        }
    };

    stage(0, 0);
    stage(1, 1);
    const int mr = lane & 15;
    const int q8 = (lane >> 4) * 8;
    for (int kt = 0; kt < NT; ++kt) {
        if (kt < NT - 1) __builtin_amdgcn_s_waitcnt(WAITCNT_VM3);
        else             __builtin_amdgcn_s_waitcnt(WAITCNT_VM0);
        __builtin_amdgcn_s_barrier();
        if (kt + 2 < NT) stage((kt + 2) % 3, kt + 2);
        const int ca = (kt % 3) * ASZ;
        const int cbb = (kt % 3) * BSZ;
        bf16x8 af[4], bfv[2];
#pragma unroll
        for (int i = 0; i < 4; ++i)
            af[i] = *(const bf16x8*)&As[ca + (wr * 64 + i * 16 + mr) * BK + q8];
#pragma unroll
        for (int j = 0; j < 2; ++j)
            bfv[j] = *(const bf16x8*)&Bs[cbb + (wc * 32 + j * 16 + mr) * BK + q8];
#pragma unroll
        for (int i = 0; i < 4; ++i)
#pragma unroll
            for (int j = 0; j < 2; ++j)
                acc[i][j] = __builtin_amdgcn_mfma_f32_16x16x32_bf16(
                    af[i], bfv[j], acc[i][j], 0, 0, 0);
    }

    const int colBase = bn * BN + wc * 32 + (lane & 15);
    const int rowBase = bm * BM + wr * 64 + (lane >> 4) * 4;
#pragma unroll
    for (int j = 0; j < 2; ++j) {
        const int coln = colBase + j * 16;
        const float bias = bhh[coln];
#pragma unroll
        for (int i = 0; i < 4; ++i) {
#pragma unroll
            for (int r = 0; r < 4; ++r) {
                const int rown = rowBase + i * 16 + r;
                const size_t oidx = (size_t)rown * H_SZ + coln;
                const float pre = acc[i][j][r] + bias + bf2f(Pb[oidx]);
                const float ht = tanhf(pre);
                const float zz = bf2f(Zb[oidx]);
                const float hh = hidden[oidx];
                out_nh[oidx] = zz * hh + (1.0f - zz) * ht;
            }
        }
    }
}

// ---------------- row-wise log_softmax over H=1024 ----------------
__global__ __launch_bounds__(256) void lsm_kernel(const float* __restrict__ nh,
                                                  float* __restrict__ out) {
    const int row = blockIdx.x;
    const int tid = threadIdx.x;
    const int wave = tid >> 6, lane = tid & 63;
    const float4 v = ((const float4*)(nh + (size_t)row * H_SZ))[tid];
    __shared__ float redm[4];
    __shared__ float reds[4];
    float m = fmaxf(fmaxf(v.x, v.y), fmaxf(v.z, v.w));
#pragma unroll
    for (int o = 32; o; o >>= 1) m = fmaxf(m, __shfl_xor(m, o));
    if (lane == 0) redm[wave] = m;
    __syncthreads();
    const float M = fmaxf(fmaxf(redm[0], redm[1]), fmaxf(redm[2], redm[3]));
    float s = __expf(v.x - M) + __expf(v.y - M) + __expf(v.z - M) + __expf(v.w - M);
#pragma unroll
    for (int o = 32; o; o >>= 1) s += __shfl_xor(s, o);
    if (lane == 0) reds[wave] = s;
    __syncthreads();
    const float S = reds[0] + reds[1] + reds[2] + reds[3];
    const float lse = M + __logf(S);
    float4 ov;
    ov.x = v.x - lse; ov.y = v.y - lse; ov.z = v.z - lse; ov.w = v.w - lse;
    ((float4*)(out + (size_t)row * H_SZ))[tid] = ov;
}

extern "C" void kernel_launch(void* const* d_in, const int* in_sizes, int n_in,
                              void* d_out, int out_size, void* d_ws, size_t ws_size,
                              hipStream_t stream) {
    const float* input  = (const float*)d_in[0];
    const float* hidden = (const float*)d_in[1];
    const float* Wir = (const float*)d_in[2];  const float* bir = (const float*)d_in[3];
    const float* Whr = (const float*)d_in[4];  const float* bhr = (const float*)d_in[5];
    const float* Wiz = (const float*)d_in[6];  const float* biz = (const float*)d_in[7];
    const float* Whz = (const float*)d_in[8];  const float* bhz = (const float*)d_in[9];
    const float* Wih = (const float*)d_in[10]; const float* bih = (const float*)d_in[11];
    const float* Whh = (const float*)d_in[12]; const float* bhh = (const float*)d_in[13];

    // workspace layout (92 MB)
    char* ws = (char*)d_ws;
    u16* Xb  = (u16*)(ws);                      // 16 MB  input bf16
    u16* Hb  = (u16*)(ws + (16u << 20));        // 16 MB  hidden bf16
    u16* Wb0 = (u16*)(ws + (32u << 20));        // 2 MB each: Wir,Whr,Wiz,Whz,Wih,Whh
    u16* Wb1 = (u16*)(ws + (34u << 20));
    u16* Wb2 = (u16*)(ws + (36u << 20));
    u16* Wb3 = (u16*)(ws + (38u << 20));
    u16* Wb4 = (u16*)(ws + (40u << 20));
    u16* Wb5 = (u16*)(ws + (42u << 20));
    u16* RHb = (u16*)(ws + (44u << 20));        // 16 MB  r*hidden bf16
    u16* Zb  = (u16*)(ws + (60u << 20));        // 16 MB  z bf16
    u16* Pb  = (u16*)(ws + (76u << 20));        // 16 MB  X Wih^T + bih, bf16

    float* out_lsm = (float*)d_out;
    float* out_nh  = (float*)d_out + (size_t)B_SZ * H_SZ;

    cvt_all<<<22528, 256, 0, stream>>>(input, hidden, Wir, Whr, Wiz, Whz, Wih, Whh,
                                       Xb, Hb, Wb0, Wb1, Wb2, Wb3, Wb4, Wb5);

    gemm_rzp<<<1536, 256, 0, stream>>>(Xb, Hb, Wb0, Wb1, Wb2, Wb3, Wb4,
                                       bir, bhr, biz, bhz, bih, hidden, RHb, Zb, Pb);

    gemm_nh<<<1024, 256, 0, stream>>>(RHb, Wb5, bhh, Pb, Zb, hidden, out_nh);

    lsm_kernel<<<B_SZ, 256, 0, stream>>>(out_nh, out_lsm);
}

// Round 5
// 356.301 us; speedup vs baseline: 1.0209x; 1.0209x over previous
//
#include <hip/hip_runtime.h>
#include <cstdint>

#define B_SZ 8192
#define IN_SZ 1024
#define H_SZ 1024

typedef unsigned short u16;
typedef __bf16 bf16_t;
typedef bf16_t bf16x8 __attribute__((ext_vector_type(8)));
typedef float floatx4 __attribute__((ext_vector_type(4)));

// s_waitcnt immediates: [3:0]=vmcnt low, [6:4]=expcnt(7=nowait), [11:8]=lgkmcnt(15=nowait)
#define WAITCNT_VM4 0xF74
#define WAITCNT_VM3 0xF73
#define WAITCNT_VM0 0xF70

__device__ __forceinline__ u16 f2bf(float f) {
    unsigned int u = __float_as_uint(f);
    u += 0x7fffu + ((u >> 16) & 1u);   // RNE
    return (u16)(u >> 16);
}
__device__ __forceinline__ float bf2f(u16 b) {
    return __uint_as_float(((unsigned int)b) << 16);
}

// async global->LDS, 16B per lane; LDS dest = wave-uniform base + lane*16
__device__ __forceinline__ void g2l16(const u16* g, u16* l) {
    __builtin_amdgcn_global_load_lds(
        (__attribute__((address_space(1))) void*)(uintptr_t)g,
        (__attribute__((address_space(3))) void*)(uint32_t)(uintptr_t)l,
        16, 0, 0);
}

// ---------------- single fp32 -> bf16 conversion dispatch ----------------
__global__ __launch_bounds__(256) void cvt_all(
    const float* __restrict__ X, const float* __restrict__ Hd,
    const float* __restrict__ w0, const float* __restrict__ w1,
    const float* __restrict__ w2, const float* __restrict__ w3,
    const float* __restrict__ w4, const float* __restrict__ w5,
    u16* __restrict__ Xb, u16* __restrict__ Hb,
    u16* __restrict__ d0, u16* __restrict__ d1, u16* __restrict__ d2,
    u16* __restrict__ d3, u16* __restrict__ d4, u16* __restrict__ d5) {
    const int b = blockIdx.x;
    const int tid = threadIdx.x;
    const float* s; u16* d; int off;
    if (b < 8192) {
        s = X; d = Xb; off = b * 256 + tid;
    } else if (b < 16384) {
        s = Hd; d = Hb; off = (b - 8192) * 256 + tid;
    } else {
        const int wb = b - 16384;
        const int w = wb >> 10;
        off = ((wb & 1023) << 8) + tid;
        switch (w) {
            case 0: s = w0; d = d0; break;
            case 1: s = w1; d = d1; break;
            case 2: s = w2; d = d2; break;
            case 3: s = w3; d = d3; break;
            case 4: s = w4; d = d4; break;
            default: s = w5; d = d5; break;
        }
    }
    float4 v = ((const float4*)s)[off];
    ushort4 o;
    o.x = f2bf(v.x); o.y = f2bf(v.y); o.z = f2bf(v.z); o.w = f2bf(v.w);
    ((ushort4*)d)[off] = o;
}

// ---------------- dispatch B: r, z, P; 1D grid 1536 ----------------
// 3-deep LDS rotation + manual vmcnt + raw s_barrier (R4 structure).
// NEW: XOR bank-deconflict swizzle. LDS stays linear (global_load_lds needs
// lane*16 dests); instead each lane fetches the 16B chunk of its row given by
// phys_chunk ^ ((row>>1)&3), and readers index the same permutation. A
// 16-lane read group then covers all 8 bank-quads (2 lanes/bank = free)
// instead of 8-way conflicts on 2 quads.
__global__ __launch_bounds__(256) void gemm_rzp(
    const u16* __restrict__ Xb, const u16* __restrict__ Hb,
    const u16* __restrict__ Wr0, const u16* __restrict__ Wr1,
    const u16* __restrict__ Wz0, const u16* __restrict__ Wz1,
    const u16* __restrict__ Wh0,
    const float* __restrict__ bir, const float* __restrict__ bhr,
    const float* __restrict__ biz, const float* __restrict__ bhz,
    const float* __restrict__ bih,
    const float* __restrict__ hidden,
    u16* __restrict__ RHb, u16* __restrict__ Zb, u16* __restrict__ Pb) {
    constexpr int BM = 128, BN = 128, BK = 32, K = 1024;
    constexpr int TSZ = BM * BK;           // 4096 u16 = 8KB per buffer
    __shared__ u16 As[3 * TSZ];            // 24KB
    __shared__ u16 Bs[3 * TSZ];            // 24KB
    const int tid = threadIdx.x;
    const int wave = tid >> 6;
    const int lane = tid & 63;
    const int idx = blockIdx.x;
    const int bn = idx & 7;                // XCD-local weight column
    const int gate = (idx >> 3) % 3;
    const int bm = idx / 24;
    const int wr = wave >> 1, wc = wave & 1;   // 2x2 waves, 64x64 each

    const u16* Bg0 = (gate == 0) ? Wr0 : (gate == 1) ? Wz0 : Wh0;
    const u16* Bg1 = (gate == 0) ? Wr1 : Wz1;   // unused when gate==2
    const int NT = (gate == 2) ? 32 : 64;

    const floatx4 z4 = {0.f, 0.f, 0.f, 0.f};
    floatx4 acc[4][4];
#pragma unroll
    for (int i = 0; i < 4; ++i)
#pragma unroll
        for (int j = 0; j < 4; ++j) acc[i][j] = z4;

    auto stage = [&](int pb, int kt) {
        const int seg = kt >> 5;
        const int k0 = (kt & 31) * BK;
        const u16* __restrict__ Ag = seg ? Hb : Xb;
        const u16* __restrict__ Bg = seg ? Bg1 : Bg0;
        const int base = pb * TSZ;
#pragma unroll
        for (int j = 0; j < 2; ++j) {
            const int c = j * 256 + wave * 64 + lane;   // 16B chunk 0..511
            const int row = c >> 2;
            const int lg = (c & 3) ^ ((row >> 1) & 3);  // swizzled source chunk
            const int ldsc = base + (j * 256 + wave * 64) * 8;  // wave-uniform
            g2l16(Ag + (size_t)(bm * BM + row) * K + k0 + lg * 8, &As[ldsc]);
            g2l16(Bg + (size_t)(bn * BN + row) * K + k0 + lg * 8, &Bs[ldsc]);
        }
    };

    stage(0, 0);
    stage(1, 1);
    const int mr = lane & 15;
    // read rows are (mult of 16)+mr -> (row>>1)&3 == (mr>>1)&3 for all frags
    const int ph = ((lane >> 4) ^ ((mr >> 1) & 3)) * 8;  // swizzled chunk offset (u16)
    for (int kt = 0; kt < NT; ++kt) {
        if (kt < NT - 1) __builtin_amdgcn_s_waitcnt(WAITCNT_VM4);
        else             __builtin_amdgcn_s_waitcnt(WAITCNT_VM0);
        __builtin_amdgcn_s_barrier();
        if (kt + 2 < NT) stage((kt + 2) % 3, kt + 2);
        const int cb = (kt % 3) * TSZ;
        bf16x8 af[4], bfv[4];
#pragma unroll
        for (int i = 0; i < 4; ++i)
            af[i] = *(const bf16x8*)&As[cb + (wr * 64 + i * 16 + mr) * BK + ph];
#pragma unroll
        for (int j = 0; j < 4; ++j)
            bfv[j] = *(const bf16x8*)&Bs[cb + (wc * 64 + j * 16 + mr) * BK + ph];
#pragma unroll
        for (int i = 0; i < 4; ++i)
#pragma unroll
            for (int j = 0; j < 4; ++j)
                acc[i][j] = __builtin_amdgcn_mfma_f32_16x16x32_bf16(
                    af[i], bfv[j], acc[i][j], 0, 0, 0);
    }

    // C/D layout: col=lane&15, row=(lane>>4)*4+reg (m89/m91 verified)
    const int colBase = bn * BN + wc * 64 + (lane & 15);
    const int rowBase = bm * BM + wr * 64 + (lane >> 4) * 4;
#pragma unroll
    for (int j = 0; j < 4; ++j) {
        const int coln = colBase + j * 16;
        float bias;
        if (gate == 0) bias = bir[coln] + bhr[coln];
        else if (gate == 1) bias = biz[coln] + bhz[coln];
        else bias = bih[coln];
#pragma unroll
        for (int i = 0; i < 4; ++i) {
#pragma unroll
            for (int r = 0; r < 4; ++r) {
                const int rown = rowBase + i * 16 + r;
                const size_t oidx = (size_t)rown * H_SZ + coln;
                const float v = acc[i][j][r] + bias;
                if (gate == 0) {
                    const float rv = 1.0f / (1.0f + __expf(-v));
                    RHb[oidx] = f2bf(rv * hidden[oidx]);
                } else if (gate == 1) {
                    Zb[oidx] = f2bf(1.0f / (1.0f + __expf(-v)));
                } else {
                    Pb[oidx] = f2bf(v);
                }
            }
        }
    }
}

// ---------------- dispatch C: new_hidden; 1D grid 1024 ----------------
// BM=128 BN=64; 3-deep rotation; same XOR swizzle.
__global__ __launch_bounds__(256) void gemm_nh(
    const u16* __restrict__ RHb, const u16* __restrict__ Whh,
    const float* __restrict__ bhh,
    const u16* __restrict__ Pb, const u16* __restrict__ Zb,
    const float* __restrict__ hidden, float* __restrict__ out_nh) {
    constexpr int BM = 128, BN = 64, BK = 32, K = 1024, NT = K / BK;
    constexpr int ASZ = BM * BK;   // 4096 u16
    constexpr int BSZ = BN * BK;   // 2048 u16
    __shared__ u16 As[3 * ASZ];    // 24KB
    __shared__ u16 Bs[3 * BSZ];    // 12KB
    const int tid = threadIdx.x;
    const int wave = tid >> 6;
    const int lane = tid & 63;
    const int bn = blockIdx.x & 15;
    const int bm = blockIdx.x >> 4;
    const int wr = wave >> 1, wc = wave & 1;   // 64 rows x 32 cols per wave

    const floatx4 z4 = {0.f, 0.f, 0.f, 0.f};
    floatx4 acc[4][2];
#pragma unroll
    for (int i = 0; i < 4; ++i)
#pragma unroll
        for (int j = 0; j < 2; ++j) acc[i][j] = z4;

    auto stage = [&](int pb, int kt) {
        const int k0 = kt * BK;
#pragma unroll
        for (int j = 0; j < 2; ++j) {
            const int c = j * 256 + wave * 64 + lane;
            const int row = c >> 2;
            const int lg = (c & 3) ^ ((row >> 1) & 3);
            const int ldsc = pb * ASZ + (j * 256 + wave * 64) * 8;
            g2l16(RHb + (size_t)(bm * BM + row) * K + k0 + lg * 8, &As[ldsc]);
        }
        {
            const int c = wave * 64 + lane;      // 0..255
            const int row = c >> 2;              // 0..63
            const int lg = (c & 3) ^ ((row >> 1) & 3);
            const int ldsc = pb * BSZ + (wave * 64) * 8;
            g2l16(Whh + (size_t)(bn * BN + row) * K + k0 + lg * 8, &Bs[ldsc]);
        }
    };

    stage(0, 0);
    stage(1, 1);
    const int mr = lane & 15;
    const int ph = ((lane >> 4) ^ ((mr >> 1) & 3)) * 8;
    for (int kt = 0; kt < NT; ++kt) {
        if (kt < NT - 1) __builtin_amdgcn_s_waitcnt(WAITCNT_VM3);
        else             __builtin_amdgcn_s_waitcnt(WAITCNT_VM0);
        __builtin_amdgcn_s_barrier();
        if (kt + 2 < NT) stage((kt + 2) % 3, kt + 2);
        const int ca = (kt % 3) * ASZ;
        const int cbb = (kt % 3) * BSZ;
        bf16x8 af[4], bfv[2];
#pragma unroll
        for (int i = 0; i < 4; ++i)
            af[i] = *(const bf16x8*)&As[ca + (wr * 64 + i * 16 + mr) * BK + ph];
#pragma unroll
        for (int j = 0; j < 2; ++j)
            bfv[j] = *(const bf16x8*)&Bs[cbb + (wc * 32 + j * 16 + mr) * BK + ph];
#pragma unroll
        for (int i = 0; i < 4; ++i)
#pragma unroll
            for (int j = 0; j < 2; ++j)
                acc[i][j] = __builtin_amdgcn_mfma_f32_16x16x32_bf16(
                    af[i], bfv[j], acc[i][j], 0, 0, 0);
    }

    const int colBase = bn * BN + wc * 32 + (lane & 15);
    const int rowBase = bm * BM + wr * 64 + (lane >> 4) * 4;
#pragma unroll
    for (int j = 0; j < 2; ++j) {
        const int coln = colBase + j * 16;
        const float bias = bhh[coln];
#pragma unroll
        for (int i = 0; i < 4; ++i) {
#pragma unroll
            for (int r = 0; r < 4; ++r) {
                const int rown = rowBase + i * 16 + r;
                const size_t oidx = (size_t)rown * H_SZ + coln;
                const float pre = acc[i][j][r] + bias + bf2f(Pb[oidx]);
                const float ht = tanhf(pre);
                const float zz = bf2f(Zb[oidx]);
                const float hh = hidden[oidx];
                out_nh[oidx] = zz * hh + (1.0f - zz) * ht;
            }
        }
    }
}

// ---------------- row-wise log_softmax over H=1024 ----------------
__global__ __launch_bounds__(256) void lsm_kernel(const float* __restrict__ nh,
                                                  float* __restrict__ out) {
    const int row = blockIdx.x;
    const int tid = threadIdx.x;
    const int wave = tid >> 6, lane = tid & 63;
    const float4 v = ((const float4*)(nh + (size_t)row * H_SZ))[tid];
    __shared__ float redm[4];
    __shared__ float reds[4];
    float m = fmaxf(fmaxf(v.x, v.y), fmaxf(v.z, v.w));
#pragma unroll
    for (int o = 32; o; o >>= 1) m = fmaxf(m, __shfl_xor(m, o));
    if (lane == 0) redm[wave] = m;
    __syncthreads();
    const float M = fmaxf(fmaxf(redm[0], redm[1]), fmaxf(redm[2], redm[3]));
    float s = __expf(v.x - M) + __expf(v.y - M) + __expf(v.z - M) + __expf(v.w - M);
#pragma unroll
    for (int o = 32; o; o >>= 1) s += __shfl_xor(s, o);
    if (lane == 0) reds[wave] = s;
    __syncthreads();
    const float S = reds[0] + reds[1] + reds[2] + reds[3];
    const float lse = M + __logf(S);
    float4 ov;
    ov.x = v.x - lse; ov.y = v.y - lse; ov.z = v.z - lse; ov.w = v.w - lse;
    ((float4*)(out + (size_t)row * H_SZ))[tid] = ov;
}

extern "C" void kernel_launch(void* const* d_in, const int* in_sizes, int n_in,
                              void* d_out, int out_size, void* d_ws, size_t ws_size,
                              hipStream_t stream) {
    const float* input  = (const float*)d_in[0];
    const float* hidden = (const float*)d_in[1];
    const float* Wir = (const float*)d_in[2];  const float* bir = (const float*)d_in[3];
    const float* Whr = (const float*)d_in[4];  const float* bhr = (const float*)d_in[5];
    const float* Wiz = (const float*)d_in[6];  const float* biz = (const float*)d_in[7];
    const float* Whz = (const float*)d_in[8];  const float* bhz = (const float*)d_in[9];
    const float* Wih = (const float*)d_in[10]; const float* bih = (const float*)d_in[11];
    const float* Whh = (const float*)d_in[12]; const float* bhh = (const float*)d_in[13];

    // workspace layout (92 MB)
    char* ws = (char*)d_ws;
    u16* Xb  = (u16*)(ws);                      // 16 MB  input bf16
    u16* Hb  = (u16*)(ws + (16u << 20));        // 16 MB  hidden bf16
    u16* Wb0 = (u16*)(ws + (32u << 20));        // 2 MB each: Wir,Whr,Wiz,Whz,Wih,Whh
    u16* Wb1 = (u16*)(ws + (34u << 20));
    u16* Wb2 = (u16*)(ws + (36u << 20));
    u16* Wb3 = (u16*)(ws + (38u << 20));
    u16* Wb4 = (u16*)(ws + (40u << 20));
    u16* Wb5 = (u16*)(ws + (42u << 20));
    u16* RHb = (u16*)(ws + (44u << 20));        // 16 MB  r*hidden bf16
    u16* Zb  = (u16*)(ws + (60u << 20));        // 16 MB  z bf16
    u16* Pb  = (u16*)(ws + (76u << 20));        // 16 MB  X Wih^T + bih, bf16

    float* out_lsm = (float*)d_out;
    float* out_nh  = (float*)d_out + (size_t)B_SZ * H_SZ;

    cvt_all<<<22528, 256, 0, stream>>>(input, hidden, Wir, Whr, Wiz, Whz, Wih, Whh,
                                       Xb, Hb, Wb0, Wb1, Wb2, Wb3, Wb4, Wb5);

    gemm_rzp<<<1536, 256, 0, stream>>>(Xb, Hb, Wb0, Wb1, Wb2, Wb3, Wb4,
                                       bir, bhr, biz, bhz, bih, hidden, RHb, Zb, Pb);

    gemm_nh<<<1024, 256, 0, stream>>>(RHb, Wb5, bhh, Pb, Zb, hidden, out_nh);

    lsm_kernel<<<B_SZ, 256, 0, stream>>>(out_nh, out_lsm);
}